// Round 1
// baseline (186.696 us; speedup 1.0000x reference)
//
#include <hip/hip_runtime.h>

#define NCC 20
#define HH  32
#define WW  32
#define AA  5
#define MM  50
#define HWC (HH*WW)   // 1024 cells per batch

// One block = 256 consecutive cells of one batch (4 blocks per batch).
// Stage this batch's GT objects in LDS; each thread scans them to build its
// cell's target (last-valid-object wins for vals; class one-hot -> bitmask,
// argmax == lowest set bit). Only conf planes (ch 20) are read for all cells;
// obj cells (~2.5%) additionally read ch21-24 per anchor + 20 cls logits of
// the best anchor. This cuts HBM traffic from 131 MB to ~6 MB.
__global__ __launch_bounds__(256) void yolo_loss(
    const float* __restrict__ out,        // [B, 125, 32, 32]
    const float* __restrict__ gt_boxes,   // [B, 50, 4]
    const float* __restrict__ anchor,     // [5, 2]
    const int*   __restrict__ gt_classes, // [B, 50]
    const int*   __restrict__ num_box,    // [B]
    float*       __restrict__ loss)       // [4]: box, conf, noobj, cls
{
    __shared__ int   s_cell[MM];
    __shared__ float s_xo[MM], s_yo[MM], s_tw[MM], s_th[MM];
    __shared__ int   s_cls[MM];
    __shared__ float s_anc[2*AA];
    __shared__ int   s_nb;
    __shared__ float s_red[4][4];

    const int tid = threadIdx.x;
    const int b   = blockIdx.x >> 2;
    const int rem = ((blockIdx.x & 3) << 8) | tid;  // cell within batch [0,1024)

    if (tid == 0) s_nb = num_box[b];
    if (tid < 2*AA) s_anc[tid] = anchor[tid];
    if (tid < MM) {
        float4 g = ((const float4*)gt_boxes)[b*MM + tid];
        float x = g.x * (float)HH;
        float y = g.y * (float)HH;
        int gx = (int)floorf(x);
        int gy = (int)floorf(y);
        s_cell[tid] = gy*WW + gx;
        s_xo[tid] = x - (float)gx;
        s_yo[tid] = y - (float)gy;
        s_tw[tid] = g.z * (float)HH;
        s_th[tid] = g.w * (float)HH;
        s_cls[tid] = gt_classes[b*MM + tid];
    }
    __syncthreads();

    int nb = s_nb; if (nb > MM) nb = MM;

    // Scan objects: ascending m => last valid object mapping here wins vals
    // (matches sequential scatter semantics); class bits accumulate (OR).
    int clsmask = 0;
    float xo = 0.f, yo = 0.f, tw = 0.f, th = 0.f;
    for (int m = 0; m < nb; ++m) {
        if (s_cell[m] == rem) {           // LDS broadcast read, conflict-free
            xo = s_xo[m]; yo = s_yo[m]; tw = s_tw[m]; th = s_th[m];
            clsmask |= 1 << s_cls[m];
        }
    }

    const float* cellp = out + ((size_t)b * (AA*(5+NCC))) * HWC + rem;

    // conf channel for all 5 anchors -- the only global read for ~97% of threads
    float pc[AA];
    float noobj_l = 0.f;
    #pragma unroll
    for (int a = 0; a < AA; ++a) {
        float cl = cellp[(a*25 + NCC) * HWC];
        float s  = 1.f / (1.f + expf(-cl));
        pc[a] = s;
        noobj_l += s * s;
    }

    float box_l = 0.f, conf_l = 0.f, cls_l = 0.f;

    if (clsmask != 0) {                   // obj cell
        const float fgx = (float)(rem & 31);
        const float fgy = (float)(rem >> 5);
        const float tbx = fgx + xo;
        const float tby = fgy + yo;

        float best_iou = -1.f;
        int   best = 0;
        float bpx = 0.f, bpy = 0.f, bpw = 0.f, bph = 0.f;
        #pragma unroll
        for (int a = 0; a < AA; ++a) {
            float t21 = cellp[(a*25 + NCC+1) * HWC];
            float t22 = cellp[(a*25 + NCC+2) * HWC];
            float t23 = cellp[(a*25 + NCC+3) * HWC];
            float t24 = cellp[(a*25 + NCC+4) * HWC];
            float px = fgx + 1.f / (1.f + expf(-t21));
            float py = fgy + 1.f / (1.f + expf(-t22));
            float pw = expf(t23) * s_anc[2*a];
            float ph = expf(t24) * s_anc[2*a+1];
            float iw = fmaxf(fminf(px + pw*0.5f, tbx + tw*0.5f)
                           - fmaxf(px - pw*0.5f, tbx - tw*0.5f), 0.f);
            float ih = fmaxf(fminf(py + ph*0.5f, tby + th*0.5f)
                           - fmaxf(py - ph*0.5f, tby - th*0.5f), 0.f);
            float inter = iw * ih;
            float uni   = pw*ph + tw*th - inter;
            float iou   = inter / fmaxf(uni, 1e-10f);
            if (iou > best_iou) {         // strict > == argmax first-occurrence
                best_iou = iou; best = a;
                bpx = px; bpy = py; bpw = pw; bph = ph;
            }
        }

        float dx = bpx - tbx;
        float dy = bpy - tby;
        float dw = sqrtf(bpw) - sqrtf(tw);
        float dh = sqrtf(bph) - sqrtf(th);
        box_l = dx*dx + dy*dy + dw*dw + dh*dh;   // obj == 1.0

        float cd = pc[best] - 1.f;               // conf target = obj = 1
        conf_l = cd * cd;

        noobj_l -= pc[best] * pc[best];          // (1 - one_hot(best)) mask

        // cls: cross-entropy at lowest set class bit (argmax of multi-hot)
        int cls_t = __ffs(clsmask) - 1;
        float mx = -1e30f, ssum = 0.f, lt = 0.f;
        #pragma unroll
        for (int i = 0; i < NCC; ++i) {
            float l = cellp[(best*25 + i) * HWC];
            if (i == cls_t) lt = l;
            float nm = fmaxf(mx, l);
            ssum = ssum * expf(mx - nm) + expf(l - nm);
            mx = nm;
        }
        cls_l = mx + logf(ssum) - lt;
    }

    // block reduction: wave64 shuffle, then cross-wave via LDS
    float v[4] = { box_l  * (5.0f/256.0f),
                   conf_l * (1.0f/256.0f),
                   noobj_l* (0.5f/256.0f),
                   cls_l  * (1.0f/256.0f) };
    const int lane = tid & 63;
    const int wid  = tid >> 6;
    #pragma unroll
    for (int k = 0; k < 4; ++k) {
        float x = v[k];
        #pragma unroll
        for (int off = 32; off > 0; off >>= 1)
            x += __shfl_down(x, off, 64);
        if (lane == 0) s_red[wid][k] = x;
    }
    __syncthreads();
    if (tid < 4) {
        float sum = s_red[0][tid] + s_red[1][tid] + s_red[2][tid] + s_red[3][tid];
        atomicAdd(&loss[tid], sum);
    }
}

extern "C" void kernel_launch(void* const* d_in, const int* in_sizes, int n_in,
                              void* d_out, int out_size, void* d_ws, size_t ws_size,
                              hipStream_t stream) {
    const float* out_t      = (const float*)d_in[0];
    const float* gt_boxes   = (const float*)d_in[1];
    const float* anchor     = (const float*)d_in[2];
    const int*   gt_classes = (const int*)d_in[3];
    const int*   num_box    = (const int*)d_in[4];
    float* loss = (float*)d_out;

    // d_out is poisoned 0xAA before every timed launch -- zero it ourselves.
    hipMemsetAsync(d_out, 0, (size_t)out_size * sizeof(float), stream);

    const int B = 256;
    yolo_loss<<<dim3(B * 4), dim3(256), 0, stream>>>(
        out_t, gt_boxes, anchor, gt_classes, num_box, loss);
}

// Round 2
// 180.867 us; speedup vs baseline: 1.0322x; 1.0322x over previous
//
#include <hip/hip_runtime.h>

#define NCC 20
#define HH  32
#define WW  32
#define AA  5
#define MM  50
#define HWC (HH*WW)   // 1024 cells per batch
#define NBLK 1024     // 4 blocks per batch

// One block = 256 consecutive cells of one batch (4 blocks per batch).
// Stage this batch's GT objects in LDS; each thread scans them to build its
// cell's target (last-valid-object wins for vals; class one-hot -> bitmask,
// argmax == lowest set bit). Only conf planes (ch 20) are read for all cells;
// obj cells (~2.5%) additionally read ch21-24 per anchor + 20 cls logits of
// the best anchor. HBM traffic ~6 MB vs 131 MB naive.
//
// Epilogue: per-block partials -> d_ws (NO atomics; 1024 blocks x 4 atomicAdd
// to one cacheline serialized at L2 and was the suspected ~30-40us cost).
__global__ __launch_bounds__(256) void yolo_loss(
    const float* __restrict__ out,        // [B, 125, 32, 32]
    const float* __restrict__ gt_boxes,   // [B, 50, 4]
    const float* __restrict__ anchor,     // [5, 2]
    const int*   __restrict__ gt_classes, // [B, 50]
    const int*   __restrict__ num_box,    // [B]
    float4*      __restrict__ partials)   // [NBLK]: (box, conf, noobj, cls)
{
    __shared__ int   s_cell[MM];
    __shared__ float s_xo[MM], s_yo[MM], s_tw[MM], s_th[MM];
    __shared__ int   s_cls[MM];
    __shared__ float s_anc[2*AA];
    __shared__ int   s_nb;
    __shared__ float s_red[4][4];

    const int tid = threadIdx.x;
    const int b   = blockIdx.x >> 2;
    const int rem = ((blockIdx.x & 3) << 8) | tid;  // cell within batch [0,1024)

    if (tid == 0) s_nb = num_box[b];
    if (tid < 2*AA) s_anc[tid] = anchor[tid];
    if (tid < MM) {
        float4 g = ((const float4*)gt_boxes)[b*MM + tid];
        float x = g.x * (float)HH;
        float y = g.y * (float)HH;
        int gx = (int)floorf(x);
        int gy = (int)floorf(y);
        s_cell[tid] = gy*WW + gx;
        s_xo[tid] = x - (float)gx;
        s_yo[tid] = y - (float)gy;
        s_tw[tid] = g.z * (float)HH;
        s_th[tid] = g.w * (float)HH;
        s_cls[tid] = gt_classes[b*MM + tid];
    }
    __syncthreads();

    int nb = s_nb; if (nb > MM) nb = MM;

    // Scan objects: ascending m => last valid object mapping here wins vals
    // (matches sequential scatter semantics); class bits accumulate (OR).
    int clsmask = 0;
    float xo = 0.f, yo = 0.f, tw = 0.f, th = 0.f;
    for (int m = 0; m < nb; ++m) {
        if (s_cell[m] == rem) {           // LDS broadcast read, conflict-free
            xo = s_xo[m]; yo = s_yo[m]; tw = s_tw[m]; th = s_th[m];
            clsmask |= 1 << s_cls[m];
        }
    }

    const float* cellp = out + ((size_t)b * (AA*(5+NCC))) * HWC + rem;

    // conf channel for all 5 anchors -- the only global read for ~97% of threads
    float pc[AA];
    float noobj_l = 0.f;
    #pragma unroll
    for (int a = 0; a < AA; ++a) {
        float cl = cellp[(a*25 + NCC) * HWC];
        float s  = 1.f / (1.f + expf(-cl));
        pc[a] = s;
        noobj_l += s * s;
    }

    float box_l = 0.f, conf_l = 0.f, cls_l = 0.f;

    if (clsmask != 0) {                   // obj cell
        const float fgx = (float)(rem & 31);
        const float fgy = (float)(rem >> 5);
        const float tbx = fgx + xo;
        const float tby = fgy + yo;

        float best_iou = -1.f;
        int   best = 0;
        float bpx = 0.f, bpy = 0.f, bpw = 0.f, bph = 0.f;
        #pragma unroll
        for (int a = 0; a < AA; ++a) {
            float t21 = cellp[(a*25 + NCC+1) * HWC];
            float t22 = cellp[(a*25 + NCC+2) * HWC];
            float t23 = cellp[(a*25 + NCC+3) * HWC];
            float t24 = cellp[(a*25 + NCC+4) * HWC];
            float px = fgx + 1.f / (1.f + expf(-t21));
            float py = fgy + 1.f / (1.f + expf(-t22));
            float pw = expf(t23) * s_anc[2*a];
            float ph = expf(t24) * s_anc[2*a+1];
            float iw = fmaxf(fminf(px + pw*0.5f, tbx + tw*0.5f)
                           - fmaxf(px - pw*0.5f, tbx - tw*0.5f), 0.f);
            float ih = fmaxf(fminf(py + ph*0.5f, tby + th*0.5f)
                           - fmaxf(py - ph*0.5f, tby - th*0.5f), 0.f);
            float inter = iw * ih;
            float uni   = pw*ph + tw*th - inter;
            float iou   = inter / fmaxf(uni, 1e-10f);
            if (iou > best_iou) {         // strict > == argmax first-occurrence
                best_iou = iou; best = a;
                bpx = px; bpy = py; bpw = pw; bph = ph;
            }
        }

        float dx = bpx - tbx;
        float dy = bpy - tby;
        float dw = sqrtf(bpw) - sqrtf(tw);
        float dh = sqrtf(bph) - sqrtf(th);
        box_l = dx*dx + dy*dy + dw*dw + dh*dh;   // obj == 1.0

        float cd = pc[best] - 1.f;               // conf target = obj = 1
        conf_l = cd * cd;

        noobj_l -= pc[best] * pc[best];          // (1 - one_hot(best)) mask

        // cls: cross-entropy at lowest set class bit (argmax of multi-hot)
        int cls_t = __ffs(clsmask) - 1;
        float mx = -1e30f, ssum = 0.f, lt = 0.f;
        #pragma unroll
        for (int i = 0; i < NCC; ++i) {
            float l = cellp[(best*25 + i) * HWC];
            if (i == cls_t) lt = l;
            float nm = fmaxf(mx, l);
            ssum = ssum * expf(mx - nm) + expf(l - nm);
            mx = nm;
        }
        cls_l = mx + logf(ssum) - lt;
    }

    // block reduction: wave64 shuffle, then cross-wave via LDS
    float v[4] = { box_l  * (5.0f/256.0f),
                   conf_l * (1.0f/256.0f),
                   noobj_l* (0.5f/256.0f),
                   cls_l  * (1.0f/256.0f) };
    const int lane = tid & 63;
    const int wid  = tid >> 6;
    #pragma unroll
    for (int k = 0; k < 4; ++k) {
        float x = v[k];
        #pragma unroll
        for (int off = 32; off > 0; off >>= 1)
            x += __shfl_down(x, off, 64);
        if (lane == 0) s_red[wid][k] = x;
    }
    __syncthreads();
    if (tid == 0) {
        float4 p;
        p.x = s_red[0][0] + s_red[1][0] + s_red[2][0] + s_red[3][0];
        p.y = s_red[0][1] + s_red[1][1] + s_red[2][1] + s_red[3][1];
        p.z = s_red[0][2] + s_red[1][2] + s_red[2][2] + s_red[3][2];
        p.w = s_red[0][3] + s_red[1][3] + s_red[2][3] + s_red[3][3];
        partials[blockIdx.x] = p;   // plain coalesced store, no contention
    }
}

// Single block: reduce NBLK float4 partials -> 4 scalars. Overwrites d_out
// (so no memset needed; d_out poison is fully overwritten every launch).
__global__ __launch_bounds__(256) void reduce_partials(
    const float4* __restrict__ partials, float* __restrict__ loss)
{
    __shared__ float s_red[4][4];
    const int tid = threadIdx.x;

    float4 a = partials[tid];
    float4 b = partials[tid + 256];
    float4 c = partials[tid + 512];
    float4 d = partials[tid + 768];
    float v[4] = { a.x + b.x + c.x + d.x,
                   a.y + b.y + c.y + d.y,
                   a.z + b.z + c.z + d.z,
                   a.w + b.w + c.w + d.w };

    const int lane = tid & 63;
    const int wid  = tid >> 6;
    #pragma unroll
    for (int k = 0; k < 4; ++k) {
        float x = v[k];
        #pragma unroll
        for (int off = 32; off > 0; off >>= 1)
            x += __shfl_down(x, off, 64);
        if (lane == 0) s_red[wid][k] = x;
    }
    __syncthreads();
    if (tid < 4)
        loss[tid] = s_red[0][tid] + s_red[1][tid] + s_red[2][tid] + s_red[3][tid];
}

extern "C" void kernel_launch(void* const* d_in, const int* in_sizes, int n_in,
                              void* d_out, int out_size, void* d_ws, size_t ws_size,
                              hipStream_t stream) {
    const float* out_t      = (const float*)d_in[0];
    const float* gt_boxes   = (const float*)d_in[1];
    const float* anchor     = (const float*)d_in[2];
    const int*   gt_classes = (const int*)d_in[3];
    const int*   num_box    = (const int*)d_in[4];
    float* loss = (float*)d_out;
    float4* partials = (float4*)d_ws;   // 1024 * 16 B = 16 KB of scratch

    yolo_loss<<<dim3(NBLK), dim3(256), 0, stream>>>(
        out_t, gt_boxes, anchor, gt_classes, num_box, partials);
    reduce_partials<<<dim3(1), dim3(256), 0, stream>>>(partials, loss);
}